// Round 7
// baseline (125.329 us; speedup 1.0000x reference)
//
#include <hip/hip_runtime.h>

// Problem constants
#define MD 4
#define PATCH 9          // 2*MD+1
#define NBAND 256        // band-compute blocks: (b, ty) = 4 * 64
// feat1/feat2: (4, 256, 64, 64) fp32
// out: (4, 4096, 64, 64) fp32 = 256 MB
//
// out[b, ty*64+tx, y, x] = sum_c f1[b,c,y,x] * f2[b,c,ty,tx]  if |ty-y|<=4 && |tx-x|<=4, else 0.
//
// Two stream-ordered kernels:
//   1) zero_kernel: unpredicated linear float4 fill of the whole 256 MB output
//      (mirrors __amd_rocclr_fillBufferAligned, measured at 7.0 TB/s on this chip).
//   2) band_kernel: computes the banded correlation and overwrites the full 64-wide
//      rows with |y-ty|<=4 (36 MB, coalesced). Stream order serializes 1 -> 2.

__global__ __launch_bounds__(256) void zero_kernel(float4* __restrict__ o4)
{
    const int total4 = 4 * 4096 * 64 * 16;   // 16,777,216 float4
    const int stride = 4096 * 256;           // 1,048,576 threads
    const float4 z4 = make_float4(0.f, 0.f, 0.f, 0.f);
    for (int i = blockIdx.x * 256 + threadIdx.x; i < total4; i += stride)
        o4[i] = z4;                           // 16 iters, perfectly coalesced
}

// Band block = 1024 threads, 16 waves = (cq, dyg): cq = channel quarter (64 ch), dyg = dy rows
// {0,1}/{2,3}/{4,5}/{6,7,8}. <=27 acc/thread (no spill), 4 waves/SIMD for latency hiding.
// Channel partials merged via LDS atomicAdd.

template<int ND>
__device__ __forceinline__ void band_work(
    const float* __restrict__ f1base,   // f1 + (b*256+cq*64)*4096 + lane
    const float* __restrict__ f2base,   // f2 + (b*256+cq*64)*4096 + ty*64 + lane
    int ty, int dy0, int lane,
    float (*sVals)[81])
{
    float acc[ND][PATCH];
#pragma unroll
    for (int i = 0; i < ND; ++i)
#pragma unroll
        for (int j = 0; j < PATCH; ++j) acc[i][j] = 0.f;

    int yoff[ND];                        // clamped row offsets; invalid rows discarded at merge
#pragma unroll
    for (int i = 0; i < ND; ++i) {
        int y = ty + dy0 + i - MD;
        y = y < 0 ? 0 : (y > 63 ? 63 : y);
        yoff[i] = y * 64;
    }

#pragma unroll 4
    for (int c = 0; c < 64; ++c) {
        const float* f1c = f1base + (size_t)c * 4096;
        float f2v = f2base[(size_t)c * 4096];         // f2[c, ty, lane]
        float f1v[ND];
#pragma unroll
        for (int i = 0; i < ND; ++i)
            f1v[i] = f1c[yoff[i]];                    // batched coalesced loads
        float sh[PATCH];
#pragma unroll
        for (int dxi = 0; dxi < PATCH; ++dxi)
            sh[dxi] = __shfl(f2v, lane - (dxi - MD), 64);   // f2[c, ty, u-dx]
#pragma unroll
        for (int i = 0; i < ND; ++i)
#pragma unroll
            for (int dxi = 0; dxi < PATCH; ++dxi)
                acc[i][dxi] = fmaf(f1v[i], sh[dxi], acc[i][dxi]);
    }

    // Merge channel partials: entry (tx,dyi,dxi) owned by lane tx+dxi-4 of the 4 cq-waves.
#pragma unroll
    for (int i = 0; i < ND; ++i) {
        int dyi = dy0 + i;
        int y = ty + dyi - MD;
        if ((unsigned)y >= 64u) continue;             // uniform per wave
#pragma unroll
        for (int dxi = 0; dxi < PATCH; ++dxi) {
            int tx = lane - (dxi - MD);
            if ((unsigned)tx < 64u)
                atomicAdd(&sVals[tx][dyi * PATCH + dxi], acc[i][dxi]);  // stride 81: conflict-free
        }
    }
}

__global__ __launch_bounds__(1024, 4) void band_kernel(
    const float* __restrict__ f1,
    const float* __restrict__ f2,
    float* __restrict__ out)
{
    const int tid = threadIdx.x;
    const int bty = blockIdx.x;       // 0..255
    const int b   = bty >> 6;         // 0..3
    const int ty  = bty & 63;         // 0..63
    const int lane = tid & 63;        // u = x position
    const int w    = tid >> 6;        // 0..15
    const int cq   = w >> 2;          // channel quarter
    const int dyg  = w & 3;           // dy group

    // sVals[tx][dyi*9+dxi] = val(tx, y=ty+dyi-4, x=tx+dxi-4)
    __shared__ float sVals[64][81];   // 20.7 KB

    for (int i = tid; i < 64 * 81; i += 1024)
        (&sVals[0][0])[i] = 0.0f;
    __syncthreads();

    const float* f1b = f1 + (size_t)(b * 256 + cq * 64) * 4096 + lane;
    const float* f2b = f2 + (size_t)(b * 256 + cq * 64) * 4096 + ty * 64 + lane;

    if      (dyg == 0) band_work<2>(f1b, f2b, ty, 0, lane, sVals);
    else if (dyg == 1) band_work<2>(f1b, f2b, ty, 2, lane, sVals);
    else if (dyg == 2) band_work<2>(f1b, f2b, ty, 4, lane, sVals);
    else               band_work<3>(f1b, f2b, ty, 6, lane, sVals);

    __syncthreads();

    // Band rows: overwrite full 64-float rows (window values + zeros elsewhere).
    float4* out4 = (float4*)(out + (size_t)(b * 4096 + ty * 64) * 4096);
    const int q4 = tid & 15;          // float4 index within a row
    const int ro = tid >> 4;          // row index step 0..63
    for (int rb = 0; rb < 64 * PATCH; rb += 64) {
        int row = rb + ro;            // row = tx*9 + dyi
        int tx  = row / PATCH;        // const divisor -> magic multiply
        int dyi = row - tx * PATCH;
        int y   = ty + dyi - MD;
        if ((unsigned)y < 64u) {
            float comp[4];
#pragma unroll
            for (int j = 0; j < 4; ++j) {
                int x  = q4 * 4 + j;
                int dx = x - tx;
                comp[j] = (dx >= -MD && dx <= MD) ? sVals[tx][dyi * PATCH + dx + MD] : 0.f;
            }
            out4[tx * 1024 + y * 16 + q4] = make_float4(comp[0], comp[1], comp[2], comp[3]);
        }
    }
}

extern "C" void kernel_launch(void* const* d_in, const int* in_sizes, int n_in,
                              void* d_out, int out_size, void* d_ws, size_t ws_size,
                              hipStream_t stream) {
    const float* f1 = (const float*)d_in[0];
    const float* f2 = (const float*)d_in[1];
    float* out = (float*)d_out;
    zero_kernel<<<4096, 256, 0, stream>>>((float4*)out);
    band_kernel<<<NBAND, 1024, 0, stream>>>(f1, f2, out);
}

// Round 8
// 122.883 us; speedup vs baseline: 1.0199x; 1.0199x over previous
//
#include <hip/hip_runtime.h>

// Problem constants
#define MD 4
#define PATCH 9          // 2*MD+1
#define NBAND 256        // band-compute blocks: (b, ty) = 4 * 64
// feat1/feat2: (4, 256, 64, 64) fp32
// out: (4, 4096, 64, 64) fp32 = 256 MB
//
// out[b, ty*64+tx, y, x] = sum_c f1[b,c,y,x] * f2[b,c,ty,tx]  if |ty-y|<=4 && |tx-x|<=4, else 0.
//
// Kernel 1: unpredicated linear fill of the whole 256 MB output (~7 TB/s regime).
// Kernel 2: band kernel overwrites the 36 MB of full rows with |y-ty|<=4.
//   f2[b,:,ty,:] staged in LDS with 4-float zero margins (72-wide rows) so the 9
//   shifted f2 reads are 9 CONSECUTIVE ds_read addresses -> no global->shuffle
//   dependency chain in the hot loop (that chain was the ~85us pole in R4-R7).

__global__ __launch_bounds__(256) void zero_kernel(float4* __restrict__ o4)
{
    const int total4 = 4 * 4096 * 64 * 16;   // 16,777,216 float4
    const int stride = 4096 * 256;
    const float4 z4 = make_float4(0.f, 0.f, 0.f, 0.f);
    for (int i = blockIdx.x * 256 + threadIdx.x; i < total4; i += stride)
        o4[i] = z4;
}

// One wave: ND dy-rows x 64 channels. sh[dxi] = f2[c, ty, lane-dxi+4] comes from the
// padded LDS row (margin zeros stand in for x outside [0,64)); f1 loads are batched,
// independent, and pipeline under #pragma unroll.
template<int ND>
__device__ __forceinline__ void band_core(
    const float* __restrict__ f1base,     // f1 + (b*256 + ch0)*4096 + lane
    const float (* __restrict__ sF2)[72], // padded rows for this wave's 64 channels
    int ty, int dy0, int lane,
    float (*sVals)[81])
{
    float acc[ND][PATCH];
#pragma unroll
    for (int i = 0; i < ND; ++i)
#pragma unroll
        for (int j = 0; j < PATCH; ++j) acc[i][j] = 0.f;

    int yoff[ND];                          // clamped; invalid rows discarded at merge
#pragma unroll
    for (int i = 0; i < ND; ++i) {
        int y = ty + dy0 + i - MD;
        y = y < 0 ? 0 : (y > 63 ? 63 : y);
        yoff[i] = y * 64;
    }

#pragma unroll 4
    for (int c = 0; c < 64; ++c) {
        const float* f1c = f1base + (size_t)c * 4096;
        float f1v[ND];
#pragma unroll
        for (int i = 0; i < ND; ++i)
            f1v[i] = f1c[yoff[i]];                    // batched coalesced global loads
        const float* row = sF2[c];
        float sh[PATCH];
#pragma unroll
        for (int dxi = 0; dxi < PATCH; ++dxi)
            sh[dxi] = row[lane + (8 - dxi)];          // 9 consecutive LDS addrs; 2/bank = free
#pragma unroll
        for (int i = 0; i < ND; ++i)
#pragma unroll
            for (int dxi = 0; dxi < PATCH; ++dxi)
                acc[i][dxi] = fmaf(f1v[i], sh[dxi], acc[i][dxi]);
    }

    // Merge channel-quarter partials; entry (tx,dyi,dxi) touched by 4 cq waves -> atomicAdd.
#pragma unroll
    for (int i = 0; i < ND; ++i) {
        int dyi = dy0 + i;
        int y = ty + dyi - MD;
        if ((unsigned)y >= 64u) continue;             // wave-uniform
#pragma unroll
        for (int dxi = 0; dxi < PATCH; ++dxi) {
            int tx = lane - (dxi - MD);
            if ((unsigned)tx < 64u)
                atomicAdd(&sVals[tx][dyi * PATCH + dxi], acc[i][dxi]);  // stride 81: conflict-free
        }
    }
}

__global__ __launch_bounds__(512, 2) void band_kernel(
    const float* __restrict__ f1,
    const float* __restrict__ f2,
    float* __restrict__ out)
{
    const int tid = threadIdx.x;
    const int bty = blockIdx.x;       // 0..255
    const int b   = bty >> 6;
    const int ty  = bty & 63;
    const int lane = tid & 63;
    const int w    = tid >> 6;        // 0..7
    const int dyh  = w & 1;           // dy half: 0 -> dyi 0..3, 1 -> dyi 4..8
    const int cq   = w >> 1;          // channel quarter 0..3

    __shared__ float sF2[128][72];    // 36,864 B: one 128-channel round, padded rows
    __shared__ float sVals[64][81];   // 20,736 B  (total 57.6 KB)

    for (int i = tid; i < 64 * 81; i += 512)
        (&sVals[0][0])[i] = 0.0f;

    const float4* f2g = (const float4*)f2 + (size_t)(b * 256) * 1024 + ty * 16;

    for (int r = 0; r < 2; ++r) {
        __syncthreads();              // sVals-zero done / previous round's reads done
        // stage f2[b, r*128+cl, ty, :] -> sF2[cl][4..68)
#pragma unroll
        for (int k = 0; k < 4; ++k) {
            int idx = k * 512 + tid;  // 0..2047
            int cl = idx >> 4, x4 = idx & 15;
            float4 v = f2g[(size_t)(r * 128 + cl) * 1024 + x4];
            *(float4*)&sF2[cl][4 + 4 * x4] = v;       // 16B-aligned (72*4 % 16 == 0)
        }
        if (tid < 256) {              // zero the 4-float margins
            int cl = tid >> 1, off = (tid & 1) ? 68 : 0;
            *(float4*)&sF2[cl][off] = make_float4(0.f, 0.f, 0.f, 0.f);
        }
        __syncthreads();

        if ((cq >> 1) == r) {         // this wave's channels are staged this round
            int chb = (cq & 1) * 64;  // local row base within sF2
            const float* f1b = f1 + (size_t)(b * 256 + r * 128 + chb) * 4096 + lane;
            if (dyh == 0) band_core<4>(f1b, &sF2[chb], ty, 0, lane, sVals);
            else          band_core<5>(f1b, &sF2[chb], ty, 4, lane, sVals);
        }
    }
    __syncthreads();

    // Overwrite band rows: full 64-float rows (window values + zeros elsewhere).
    float4* out4 = (float4*)(out + (size_t)(b * 4096 + ty * 64) * 4096);
    const int q4 = tid & 15;          // float4 index within a row
    const int ro = tid >> 4;          // 0..31
    for (int rb = 0; rb < 64 * PATCH; rb += 32) {
        int row = rb + ro;            // row = tx*9 + dyi
        int tx  = row / PATCH;
        int dyi = row - tx * PATCH;
        int y   = ty + dyi - MD;
        if ((unsigned)y < 64u) {
            float comp[4];
#pragma unroll
            for (int j = 0; j < 4; ++j) {
                int x  = q4 * 4 + j;
                int dx = x - tx;
                comp[j] = (dx >= -MD && dx <= MD) ? sVals[tx][dyi * PATCH + dx + MD] : 0.f;
            }
            out4[tx * 1024 + y * 16 + q4] = make_float4(comp[0], comp[1], comp[2], comp[3]);
        }
    }
}

extern "C" void kernel_launch(void* const* d_in, const int* in_sizes, int n_in,
                              void* d_out, int out_size, void* d_ws, size_t ws_size,
                              hipStream_t stream) {
    const float* f1 = (const float*)d_in[0];
    const float* f2 = (const float*)d_in[1];
    float* out = (float*)d_out;
    zero_kernel<<<4096, 256, 0, stream>>>((float4*)out);
    band_kernel<<<NBAND, 512, 0, stream>>>(f1, f2, out);
}

// Round 9
// 92.499 us; speedup vs baseline: 1.3549x; 1.3285x over previous
//
#include <hip/hip_runtime.h>

// Problem constants
#define MD 4
#define PATCH 9          // 2*MD+1
#define NBAND 256        // band-compute blocks: (b, ty) = 4 * 64
#define NZERO 1024       // zero-streaming blocks
#define BT 1024          // threads per block (16 waves)
// feat1/feat2: (4, 256, 64, 64) fp32
// out: (4, 4096, 64, 64) fp32 = 256 MB
//
// out[b, ty*64+tx, y, x] = sum_c f1[b,c,y,x] * f2[b,c,ty,tx]  if |ty-y|<=4 && |tx-x|<=4, else 0.
//
// Fused kernel, row-disjoint partition:
//   zero blocks: rows |y-ty|>4 (~220 MB predicated float4 stream)
//   band blocks: rows |y-ty|<=4 (~36 MB computed)
// Band block: stage ALL of f2[b,:,ty,:] into padded 72-wide LDS rows (margins = 0), ONE
// barrier, then 16 waves (4/SIMD, full TLP) each do 64 channels x 2-3 dy rows:
// batched f1 global loads + 9 consecutive ds_reads (no load->shuffle chain, no in-loop
// barriers). Merge via LDS atomicAdd (stride 81 = conflict-free), then coalesced writeout.

template<int ND>
__device__ __forceinline__ void band_core(
    const float* __restrict__ f1base,     // f1 + (b*256 + cq*64)*4096 + lane
    const float (* __restrict__ sF2)[72], // this wave's 64 padded channel rows
    int ty, int dy0, int lane,
    float (*sVals)[81])
{
    float acc[ND][PATCH];
#pragma unroll
    for (int i = 0; i < ND; ++i)
#pragma unroll
        for (int j = 0; j < PATCH; ++j) acc[i][j] = 0.f;

    int yoff[ND];                          // clamped; invalid rows discarded at merge
#pragma unroll
    for (int i = 0; i < ND; ++i) {
        int y = ty + dy0 + i - MD;
        y = y < 0 ? 0 : (y > 63 ? 63 : y);
        yoff[i] = y * 64;
    }

#pragma unroll 4
    for (int c = 0; c < 64; ++c) {
        const float* f1c = f1base + (size_t)c * 4096;
        float f1v[ND];
#pragma unroll
        for (int i = 0; i < ND; ++i)
            f1v[i] = f1c[yoff[i]];                    // batched coalesced global loads
        const float* wp = &sF2[c][lane];
        float sh[PATCH];
#pragma unroll
        for (int dxi = 0; dxi < PATCH; ++dxi)
            sh[dxi] = wp[8 - dxi];                    // f2[c,ty,lane-dxi+4]; margins give 0
#pragma unroll
        for (int i = 0; i < ND; ++i)
#pragma unroll
            for (int dxi = 0; dxi < PATCH; ++dxi)
                acc[i][dxi] = fmaf(f1v[i], sh[dxi], acc[i][dxi]);
    }

    // Merge the 4 channel-quarter partials per entry.
#pragma unroll
    for (int i = 0; i < ND; ++i) {
        int dyi = dy0 + i;
        int y = ty + dyi - MD;
        if ((unsigned)y >= 64u) continue;             // wave-uniform
#pragma unroll
        for (int dxi = 0; dxi < PATCH; ++dxi) {
            int tx = lane - (dxi - MD);
            if ((unsigned)tx < 64u)
                atomicAdd(&sVals[tx][dyi * PATCH + dxi], acc[i][dxi]);  // stride 81: conflict-free
        }
    }
}

__global__ __launch_bounds__(BT, 4) void cv_kernel(
    const float* __restrict__ f1,
    const float* __restrict__ f2,
    float* __restrict__ out)
{
    const int tid = threadIdx.x;

    // ---------------- zero-streaming blocks ----------------
    if (blockIdx.x >= NBAND) {
        // float4 index i: bits [0:4)=x4, [4:10)=y, [10:16)=tx, [16:22)=ty, [22:24)=b
        float4* o4 = (float4*)out;
        const float4 z4 = make_float4(0.f, 0.f, 0.f, 0.f);
        const int total4 = 4 * 4096 * 64 * 16;            // 16,777,216
        const int stride = NZERO * BT;
        for (int i = (blockIdx.x - NBAND) * BT + tid; i < total4; i += stride) {
            int y  = (i >> 4) & 63;
            int ty = (i >> 16) & 63;
            int dy = y - ty;
            if (dy < -MD || dy > MD)
                o4[i] = z4;
        }
        return;
    }

    // ---------------- band-compute blocks ----------------
    const int bty = blockIdx.x;       // 0..255
    const int b   = bty >> 6;
    const int ty  = bty & 63;
    const int lane = tid & 63;        // u = x position
    const int w    = tid >> 6;        // 0..15
    const int cq   = w >> 2;          // channel quarter
    const int dyg  = w & 3;           // dy group: {0,1}/{2,3}/{4,5}/{6,7,8}

    __shared__ float sF2[256][72];    // 73,728 B: all channels, padded rows (margins 0)
    __shared__ float sVals[64][81];   // 20,736 B: sVals[tx][dyi*9+dxi]

    for (int i = tid; i < 64 * 81; i += BT)
        (&sVals[0][0])[i] = 0.0f;

    // stage f2[b, c, ty, :] -> sF2[c][4..68) for all 256 channels
    const float4* f2g = (const float4*)f2 + (size_t)(b * 256) * 1024 + ty * 16;
#pragma unroll
    for (int k = 0; k < 4; ++k) {
        int idx = k * BT + tid;       // 0..4095
        int cl = idx >> 4, x4 = idx & 15;
        *(float4*)&sF2[cl][4 + 4 * x4] = f2g[(size_t)cl * 1024 + x4];   // 16B-aligned (72%4==0)
    }
    if (tid < 512) {                  // zero the 4-float margins
        int cl = tid >> 1, off = (tid & 1) ? 68 : 0;
        *(float4*)&sF2[cl][off] = make_float4(0.f, 0.f, 0.f, 0.f);
    }
    __syncthreads();                  // single barrier before compute

    const float* f1b = f1 + (size_t)(b * 256 + cq * 64) * 4096 + lane;

    if      (dyg == 0) band_core<2>(f1b, &sF2[cq * 64], ty, 0, lane, sVals);
    else if (dyg == 1) band_core<2>(f1b, &sF2[cq * 64], ty, 2, lane, sVals);
    else if (dyg == 2) band_core<2>(f1b, &sF2[cq * 64], ty, 4, lane, sVals);
    else               band_core<3>(f1b, &sF2[cq * 64], ty, 6, lane, sVals);

    __syncthreads();

    // Band rows: full 64-float rows (9-wide value window, zeros elsewhere).
    float4* out4 = (float4*)(out + (size_t)(b * 4096 + ty * 64) * 4096);
    const int q4 = tid & 15;          // float4 index within a row
    const int ro = tid >> 4;          // 0..63
    for (int rb = 0; rb < 64 * PATCH; rb += 64) {
        int row = rb + ro;            // row = tx*9 + dyi
        int tx  = row / PATCH;        // const divisor -> magic multiply
        int dyi = row - tx * PATCH;
        int y   = ty + dyi - MD;
        if ((unsigned)y < 64u) {
            float comp[4];
#pragma unroll
            for (int j = 0; j < 4; ++j) {
                int x  = q4 * 4 + j;
                int dx = x - tx;
                comp[j] = (dx >= -MD && dx <= MD) ? sVals[tx][dyi * PATCH + dx + MD] : 0.f;
            }
            out4[tx * 1024 + y * 16 + q4] = make_float4(comp[0], comp[1], comp[2], comp[3]);
        }
    }
}

extern "C" void kernel_launch(void* const* d_in, const int* in_sizes, int n_in,
                              void* d_out, int out_size, void* d_ws, size_t ws_size,
                              hipStream_t stream) {
    const float* f1 = (const float*)d_in[0];
    const float* f2 = (const float*)d_in[1];
    float* out = (float*)d_out;
    cv_kernel<<<NBAND + NZERO, BT, 0, stream>>>(f1, f2, out);
}